// Round 8
// baseline (165.310 us; speedup 1.0000x reference)
//
#include <hip/hip_runtime.h>
#include <hip/hip_bf16.h>
#include <cstdint>

typedef __attribute__((ext_vector_type(8))) short short8;
typedef __attribute__((ext_vector_type(4))) short short4v;
typedef __attribute__((ext_vector_type(4))) float f32x4;
typedef __attribute__((ext_vector_type(16))) float f32x16;
typedef __attribute__((ext_vector_type(4))) unsigned int u32x4;
typedef unsigned short ushort_t;
typedef unsigned int uint32;

#define DEVI static __device__ __forceinline__

DEVI ushort_t f2bf(float f){
  uint32 u = __builtin_bit_cast(uint32, f);
  u += 0x7FFFu + ((u >> 16) & 1u);
  return (ushort_t)(u >> 16);
}
DEVI float bf2f(ushort_t s){
  uint32 u = ((uint32)s) << 16;
  return __builtin_bit_cast(float, u);
}
DEVI uint32 cvtpk_bf16(float lo, float hi){
  uint32 r;
  asm("v_cvt_pk_bf16_f32 %0, %1, %2" : "=v"(r) : "v"(lo), "v"(hi));
  return r;
}
DEVI void plswap(uint32& a, uint32& b){
  asm("v_permlane32_swap_b32 %0, %1" : "+v"(a), "+v"(b));
}

typedef __attribute__((address_space(1))) const uint32 g_u32;
typedef __attribute__((address_space(3))) uint32 l_u32;
#define GL_LDS16(gp, lp) __builtin_amdgcn_global_load_lds((g_u32*)(gp), (l_u32*)(lp), 16, 0, 0)

#define MFMA16(a, b, c) __builtin_amdgcn_mfma_f32_16x16x32_bf16(a, b, c, 0, 0, 0)

// ---------------- fp32 -> bf16 conversion (x and the 4 weights, QKV packed) ----------------
__global__ __launch_bounds__(256) void convert_all(
    const float* __restrict__ x, const float* __restrict__ wq, const float* __restrict__ wk,
    const float* __restrict__ wv, const float* __restrict__ wo,
    ushort_t* __restrict__ xb, ushort_t* __restrict__ wqkv, ushort_t* __restrict__ wob){
  int bid = blockIdx.x;
  const float* src; ushort_t* dst; long base;
  if (bid < 4096){ src = x; dst = xb; base = (long)bid * 2048; }
  else {
    int r = bid - 4096; int sel = r >> 9; int o = r & 511;
    src = sel==0?wq: sel==1?wk: sel==2?wv: wo;
    dst = (sel<3) ? (wqkv + (long)sel * 1048576) : wob;
    base = (long)o * 2048;
  }
  long i = base + (long)threadIdx.x * 8;
  const float* p = src + i;
  float4 a = *(const float4*)p;
  float4 b = *(const float4*)(p + 4);
  short8 v;
  v[0]=(short)f2bf(a.x); v[1]=(short)f2bf(a.y); v[2]=(short)f2bf(a.z); v[3]=(short)f2bf(a.w);
  v[4]=(short)f2bf(b.x); v[5]=(short)f2bf(b.y); v[6]=(short)f2bf(b.z); v[7]=(short)f2bf(b.w);
  *(short8*)(dst + i) = v;
}

// ---------------- RoPE cos/sin table: [2048 tok][32 j] float2 ----------------
__global__ __launch_bounds__(256) void rope_table(float2* __restrict__ tab){
  const int idx = blockIdx.x * 256 + threadIdx.x;    // 65536
  const int tok = idx >> 5, j = idx & 31;
  const float theta = exp2f(-(float)j * 0.4152410118609203f);   // log2(10000)/32
  const float ang = (float)(tok + 1) * theta;
  float s, c;
  sincosf(ang, &s, &c);
  tab[idx] = make_float2(c, s);
}

// ---------------- QKV GEMM, 256x128 tile, BK=64, tri-buffered 2-phase ----------------
// Grid 768 = 3 blocks/CU uniform. 8 waves as 4M x 2N (wave = 64x64, head-aligned).
// LDS: 3 bufs x (A 256x64 | B 128x64) = 144 KB. Staging for tile t+2 issued at
// tile t (2 A-loads + 1 B-load per kk-slice); ONE vmcnt(6) per K-tile (end of
// ph1), never 0 mid-loop. Chunk-XOR swizzle f(r)=(r>>1)&3 on both sides.
__global__ __launch_bounds__(512, 2) void gemm_qkv(
    const ushort_t* __restrict__ A, const ushort_t* __restrict__ Bw,
    const float* __restrict__ bq, const float* __restrict__ bk, const float* __restrict__ bv,
    const float2* __restrict__ tab,
    ushort_t* __restrict__ Qb, ushort_t* __restrict__ Kb, ushort_t* __restrict__ Vt){
  __shared__ __align__(16) ushort_t S[73728];   // 144 KB
  const int tid = threadIdx.x;
  const int w = tid >> 6, l = tid & 63, lr = l & 15, lg = l >> 4;
  const int wm = w >> 1, wn = w & 1;            // 4M x 2N
  const int bid = (blockIdx.x & 7) * 96 + (blockIdx.x >> 3);   // 768 = 8*96 bijective
  const int bm = bid / 24, bn = bid % 24;
  const int m0 = bm << 8, n0 = bn << 7;
  // staging: thread covers row tid>>2 (+128 for A's 2nd load), 16B chunk tid&3
  const int rbase = tid >> 2;
  const int swzk = (tid & 3) ^ ((tid >> 3) & 3);
  const ushort_t* aS = A  + (long)(m0 + rbase) * 1024 + swzk * 8;
  const ushort_t* bS = Bw + (long)(n0 + rbase) * 1024 + swzk * 8;
  // ds_read swizzled slot
  const int slot = (lg ^ ((lr >> 1) & 3)) << 3;
  const int arow = wm * 64 + lr;          // + mi*16
  const int brow = wn * 64 + lr;          // + nc*16
  f32x4 acc[4][4] = {};

#define STGA(kk, t, bf_) do{ \
    const ushort_t* _s = aS + (long)(t)*64 + (kk)*32; \
    ushort_t* _d = &S[(bf_)*24576 + (kk)*8192 + tid*8]; \
    GL_LDS16(_s,          _d); \
    GL_LDS16(_s + 131072, _d + 4096); }while(0)
#define STGB(kk, t, bf_) do{ \
    GL_LDS16(bS + (long)(t)*64 + (kk)*32, \
             &S[(bf_)*24576 + 16384 + (kk)*4096 + tid*8]); }while(0)

  // prologue: tiles 0 and 1 fully issued (12 loads); tile 0 resident
  STGA(0,0,0); STGB(0,0,0); STGA(1,0,0); STGB(1,0,0);
  STGA(0,1,1); STGB(0,1,1); STGA(1,1,1); STGB(1,1,1);
  asm volatile("s_waitcnt vmcnt(6)" ::: "memory");
  __builtin_amdgcn_s_barrier();

  int buf = 0;
  for (int t = 0; t < 16; ++t){
    const int nstg = (buf >= 1) ? buf - 1 : 2;     // (t+2)%3
    const ushort_t* SA = &S[buf * 24576];
    const ushort_t* SB = &S[buf * 24576 + 16384];
    short8 af[4], bfv[4];
    // ---- phase 0 (kk0)
#pragma unroll
    for (int mi = 0; mi < 4; ++mi) af[mi]  = *(const short8*)&SA[(arow + mi*16)*32 + slot];
#pragma unroll
    for (int nc = 0; nc < 4; ++nc) bfv[nc] = *(const short8*)&SB[(brow + nc*16)*32 + slot];
    if (t < 14){ STGA(0, t+2, nstg); STGB(0, t+2, nstg); }
    __builtin_amdgcn_s_barrier();
    __builtin_amdgcn_s_setprio(1);
#pragma unroll
    for (int mi = 0; mi < 4; ++mi)
#pragma unroll
      for (int nc = 0; nc < 4; ++nc)
        acc[mi][nc] = MFMA16(af[mi], bfv[nc], acc[mi][nc]);
    __builtin_amdgcn_s_setprio(0);
    __builtin_amdgcn_s_barrier();
    // ---- phase 1 (kk1)
#pragma unroll
    for (int mi = 0; mi < 4; ++mi) af[mi]  = *(const short8*)&SA[8192 + (arow + mi*16)*32 + slot];
#pragma unroll
    for (int nc = 0; nc < 4; ++nc) bfv[nc] = *(const short8*)&SB[4096 + (brow + nc*16)*32 + slot];
    if (t < 14){ STGA(1, t+2, nstg); STGB(1, t+2, nstg); }
    __builtin_amdgcn_s_barrier();
    __builtin_amdgcn_s_setprio(1);
#pragma unroll
    for (int mi = 0; mi < 4; ++mi)
#pragma unroll
      for (int nc = 0; nc < 4; ++nc)
        acc[mi][nc] = MFMA16(af[mi], bfv[nc], acc[mi][nc]);
    __builtin_amdgcn_s_setprio(0);
    if (t < 14)       asm volatile("s_waitcnt vmcnt(6)" ::: "memory");  // tile t+1 resident
    else if (t == 14) asm volatile("s_waitcnt vmcnt(0)" ::: "memory");  // tile 15 resident
    __builtin_amdgcn_s_barrier();
    buf = (buf >= 2) ? 0 : buf + 1;
  }
#undef STGA
#undef STGB

  // epilogue: bias + rope + scatter (wave spans exactly one head's 64 dims)
  const int colX = n0 + (wn << 6);
  const int sel = colX >> 10;                // 0=Q 1=K 2=V
  const int h = (colX >> 6) & 15;
  const int cB = (colX & 1023) + lr;
  if (sel < 2){
    ushort_t* dst = sel ? Kb : Qb;
    const float* bp = sel ? bk : bq;
    const float bvs[4] = {bp[cB], bp[cB+16], bp[cB+32], bp[cB+48]};
#pragma unroll
    for (int mi = 0; mi < 4; ++mi){
      const int row0 = m0 + (wm << 6) + mi*16 + lg*4;
#pragma unroll
      for (int i = 0; i < 4; ++i){
        const int r = row0 + i;
        const int b = r >> 11, tok = r & 2047;
#pragma unroll
        for (int nc = 0; nc < 2; ++nc){
          const int j = nc*16 + lr;
          const float2 cs = tab[tok*32 + j];
          const float v0 = acc[mi][nc][i]   + bvs[nc];
          const float v1 = acc[mi][nc+2][i] + bvs[nc+2];
          const long base = (((long)((b<<4) + h) * 2048 + tok) << 6) + j;
          dst[base]      = f2bf(v0 * cs.x - v1 * cs.y);
          dst[base + 32] = f2bf(v1 * cs.x + v0 * cs.y);
        }
      }
    }
  } else {
    const float bvs[4] = {bv[cB], bv[cB+16], bv[cB+32], bv[cB+48]};
#pragma unroll
    for (int mi = 0; mi < 4; ++mi){
      const int row0 = m0 + (wm << 6) + mi*16 + lg*4;
#pragma unroll
      for (int nc = 0; nc < 4; ++nc){
        const int d = nc*16 + lr;
#pragma unroll
        for (int i = 0; i < 4; ++i){
          const int r = row0 + i;
          const int b = r >> 11, tok = r & 2047;
          Vt[((long)((b<<4) + h) * 64 + d) * 2048 + tok] = f2bf(acc[mi][nc][i] + bvs[nc]);
        }
      }
    }
  }
}

// ---------------- output GEMM: C[M,1024] = A[M,1024] @ B[1024,1024]^T + bias (fp32 out) ----------------
__global__ __launch_bounds__(256) void gemm_out(
    const ushort_t* __restrict__ A, const ushort_t* __restrict__ Bw,
    const float* __restrict__ bias, float* __restrict__ Cout){
  __shared__ ushort_t As[4096];
  __shared__ ushort_t Bs[4096];
  const int tid = threadIdx.x, l = tid & 63, w = tid >> 6;
  const int lr = l & 15, lg = l >> 4;
  const int bid = (blockIdx.x & 7) * 64 + (blockIdx.x >> 3);    // XCD swizzle (512 = 8*64)
  const int bm = bid >> 3, bn = bid & 7;
  const int m0 = bm << 7, n0 = bn << 7;
  const int wm = (w >> 1) << 6, wn = (w & 1) << 6;
  f32x4 acc[4][4] = {};
  const ushort_t* aS = A + (long)(m0 + (tid >> 2)) * 1024 + (tid & 3) * 8;
  const ushort_t* bS = Bw + (long)(n0 + (tid >> 2)) * 1024 + (tid & 3) * 8;
  const long skip = (long)64 * 1024;
  for (int kt = 0; kt < 32; ++kt){
    GL_LDS16(aS,        &As[w * 512]);
    GL_LDS16(aS + skip, &As[2048 + w * 512]);
    GL_LDS16(bS,        &Bs[w * 512]);
    GL_LDS16(bS + skip, &Bs[2048 + w * 512]);
    aS += 32; bS += 32;
    __syncthreads();
    short8 af[4], bfr[4];
#pragma unroll
    for (int mi = 0; mi < 4; ++mi) af[mi]  = *(const short8*)&As[(wm + mi*16 + lr)*32 + lg*8];
#pragma unroll
    for (int ni = 0; ni < 4; ++ni) bfr[ni] = *(const short8*)&Bs[(wn + ni*16 + lr)*32 + lg*8];
#pragma unroll
    for (int mi = 0; mi < 4; ++mi)
#pragma unroll
      for (int ni = 0; ni < 4; ++ni)
        acc[mi][ni] = MFMA16(af[mi], bfr[ni], acc[mi][ni]);
    __syncthreads();
  }
  const int colBase = n0 + wn + lr;
#pragma unroll
  for (int mi = 0; mi < 4; ++mi){
    const int row0 = m0 + wm + mi*16 + lg*4;
#pragma unroll
    for (int ni = 0; ni < 4; ++ni){
      const int col = colBase + ni*16;
      const float bvv = bias[col];
#pragma unroll
      for (int i = 0; i < 4; ++i)
        Cout[(long)(row0 + i) * 1024 + col] = acc[mi][ni][i] + bvv;
    }
  }
}

// ---------------- flash attention (causal), 8-wave block, LDS-staged K/V ----------------
__global__ __launch_bounds__(512, 4) void attn(
    const ushort_t* __restrict__ Qb, const ushort_t* __restrict__ Kb,
    const ushort_t* __restrict__ Vt, ushort_t* __restrict__ yb){
  __shared__ __align__(16) ushort_t Ks[2][2048];
  __shared__ __align__(16) ushort_t Vs[2][2048];
  const int tid = threadIdx.x;
  const int w = tid >> 6, l = tid & 63;
  const int lq = l & 31;
  const int hi = l >> 5;
  const int xcd = blockIdx.x & 7;
  const int idx = blockIdx.x >> 3;          // 0..63
  const int hi5 = idx >> 5;                 // 0/1
  const int bh  = (xcd << 3) + ((idx >> 3) & 3) + hi5 * 4;
  const int qj  = hi5 ? (idx & 7) : 7 - (idx & 7);
  const int qc = (qj << 3) + w;
  const int q0 = qc << 5;
  const int ktmax = (qj << 3) + 7;
  const ushort_t* Qh = Qb + (long)bh * 2048 * 64;
  const ushort_t* Kh = Kb + (long)bh * 2048 * 64;
  const ushort_t* Vth = Vt + (long)bh * 64 * 2048;
  const int h8 = hi * 8;

  const ushort_t* qp = &Qh[(long)(q0 + lq) * 64 + h8];
  short8 qf0 = *(const short8*)(qp);
  short8 qf1 = *(const short8*)(qp + 16);
  short8 qf2 = *(const short8*)(qp + 32);
  short8 qf3 = *(const short8*)(qp + 48);

  const int stg_is_v = (w >= 4);
  long stg_src_off; int stg_dst_off;
  if (!stg_is_v){
    const int row = (w << 3) + (l >> 3);               // 0..31
    const int cl  = (l & 7) ^ (row & 7);
    stg_src_off = ((long)row << 6) + (cl << 3);
    stg_dst_off = (w << 9) + (l << 3);
  } else {
    const int row = ((w - 4) << 3) + (l >> 3);         // 0..31
    const int cl  = (l & 7) ^ (row & 7);
    const int dd  = row + ((cl & 4) << 3);
    stg_src_off = ((long)dd << 11) + ((cl & 3) << 3);
    stg_dst_off = ((w - 4) << 9) + (l << 3);
  }

  f32x16 o0 = {}, o1 = {};
  float lsum = 0.f;
  const float cl2 = 0.1803368801111204f;

  if (!stg_is_v) GL_LDS16(Kh + stg_src_off,  &Ks[0][stg_dst_off]);
  else           GL_LDS16(Vth + stg_src_off, &Vs[0][stg_dst_off]);
  __syncthreads();

  int cur = 0;
  for (int kt = 0; kt <= ktmax; ++kt){
    if (kt < ktmax){
      const int k0n = (kt + 1) << 5;
      if (!stg_is_v) GL_LDS16(Kh + ((long)k0n << 6) + stg_src_off, &Ks[cur ^ 1][stg_dst_off]);
      else           GL_LDS16(Vth + k0n + stg_src_off,             &Vs[cur ^ 1][stg_dst_off]);
    }
    if (kt <= qc){
      const int swk = lq & 7;
      const ushort_t* kr = &Ks[cur][lq << 6];
      short8 kf0 = *(const short8*)&kr[((hi    ) ^ swk) << 3];
      short8 kf1 = *(const short8*)&kr[((2 + hi) ^ swk) << 3];
      short8 kf2 = *(const short8*)&kr[((4 + hi) ^ swk) << 3];
      short8 kf3 = *(const short8*)&kr[((6 + hi) ^ swk) << 3];
      const ushort_t* vr = &Vs[cur][lq << 6];
      short8 vf00 = *(const short8*)&vr[((hi    ) ^ swk) << 3];
      short8 vf01 = *(const short8*)&vr[((2 + hi) ^ swk) << 3];
      short8 vf10 = *(const short8*)&vr[((4 + hi) ^ swk) << 3];
      short8 vf11 = *(const short8*)&vr[((6 + hi) ^ swk) << 3];
      f32x16 s = {};
      s = __builtin_amdgcn_mfma_f32_32x32x16_bf16(kf0, qf0, s, 0, 0, 0);
      s = __builtin_amdgcn_mfma_f32_32x32x16_bf16(kf1, qf1, s, 0, 0, 0);
      s = __builtin_amdgcn_mfma_f32_32x32x16_bf16(kf2, qf2, s, 0, 0, 0);
      s = __builtin_amdgcn_mfma_f32_32x32x16_bf16(kf3, qf3, s, 0, 0, 0);
      if (kt == qc){
#pragma unroll
        for (int r = 0; r < 16; ++r){
          const int rk = (r & 3) + 8 * (r >> 2) + 4 * hi;
          if (rk > lq) s[r] = -1e30f;
        }
      }
#pragma unroll
      for (int r = 0; r < 16; ++r) s[r] = __builtin_amdgcn_exp2f(__builtin_fmaf(s[r], cl2, -2.0f));
      {
        float t0 = (s[0] + s[1]) + (s[2] + s[3]);
        float t1 = (s[4] + s[5]) + (s[6] + s[7]);
        float t2 = (s[8] + s[9]) + (s[10] + s[11]);
        float t3 = (s[12] + s[13]) + (s[14] + s[15]);
        lsum += (t0 + t1) + (t2 + t3);
      }
      uint32 a0 = cvtpk_bf16(s[0], s[1]),  b0 = cvtpk_bf16(s[4], s[5]);
      uint32 a1 = cvtpk_bf16(s[2], s[3]),  b1 = cvtpk_bf16(s[6], s[7]);
      uint32 a2 = cvtpk_bf16(s[8], s[9]),  b2 = cvtpk_bf16(s[12], s[13]);
      uint32 a3 = cvtpk_bf16(s[10], s[11]),b3 = cvtpk_bf16(s[14], s[15]);
      plswap(a0, b0);
      plswap(a1, b1);
      plswap(a2, b2);
      plswap(a3, b3);
      u32x4 pc0 = {a0, a1, b0, b1};
      u32x4 pc1 = {a2, a3, b2, b3};
      short8 pb0 = __builtin_bit_cast(short8, pc0);
      short8 pb1 = __builtin_bit_cast(short8, pc1);
      o0 = __builtin_amdgcn_mfma_f32_32x32x16_bf16(vf00, pb0, o0, 0, 0, 0);
      o0 = __builtin_amdgcn_mfma_f32_32x32x16_bf16(vf01, pb1, o0, 0, 0, 0);
      o1 = __builtin_amdgcn_mfma_f32_32x32x16_bf16(vf10, pb0, o1, 0, 0, 0);
      o1 = __builtin_amdgcn_mfma_f32_32x32x16_bf16(vf11, pb1, o1, 0, 0, 0);
    }
    __syncthreads();
    cur ^= 1;
  }
  lsum += __shfl_xor(lsum, 32);
  const float inv = 1.0f / lsum;
  const int b = bh >> 4, h = bh & 15;
  const int tok = q0 + lq;
  ushort_t* yrow = yb + (long)(b * 2048 + tok) * 1024 + h * 64;
#pragma unroll
  for (int g = 0; g < 4; ++g){
    short4v p0, p1;
#pragma unroll
    for (int j = 0; j < 4; ++j){
      p0[j] = (short)f2bf(o0[4*g + j] * inv);
      p1[j] = (short)f2bf(o1[4*g + j] * inv);
    }
    *(short4v*)&yrow[8*g + 4*hi]      = p0;
    *(short4v*)&yrow[32 + 8*g + 4*hi] = p1;
  }
}

// ---------------- launch ----------------
extern "C" void kernel_launch(void* const* d_in, const int* in_sizes, int n_in,
                              void* d_out, int out_size, void* d_ws, size_t ws_size,
                              hipStream_t stream){
  const float* x  = (const float*)d_in[0];
  const float* Wq = (const float*)d_in[1];
  const float* bq = (const float*)d_in[2];
  const float* Wk = (const float*)d_in[3];
  const float* bk = (const float*)d_in[4];
  const float* Wv = (const float*)d_in[5];
  const float* bv = (const float*)d_in[6];
  const float* Wo = (const float*)d_in[7];
  const float* bo = (const float*)d_in[8];
  char* ws = (char*)d_ws;
  ushort_t* xb   = (ushort_t*)(ws);                      // 16 MB; reused as yb after attn
  ushort_t* wqkv = (ushort_t*)(ws + 16777216);           // 6 MB (Q,K,V packed)
  ushort_t* wob  = (ushort_t*)(ws + 23068672);           // 2 MB
  float2*   tab  = (float2*)  (ws + 25165824);           // 512 KB
  ushort_t* Qb   = (ushort_t*)(ws + 25690112);           // 16 MB
  ushort_t* Kb   = (ushort_t*)(ws + 42467328);           // 16 MB
  ushort_t* Vt   = (ushort_t*)(ws + 59244544);           // 16 MB
  ushort_t* yb   = xb;

  convert_all<<<6144, 256, 0, stream>>>(x, Wq, Wk, Wv, Wo, xb, wqkv, wob);
  rope_table<<<256, 256, 0, stream>>>(tab);
  gemm_qkv<<<768, 512, 0, stream>>>(xb, wqkv, bq, bk, bv, tab, Qb, Kb, Vt);
  attn<<<512, 512, 0, stream>>>(Qb, Kb, Vt, yb);
  gemm_out<<<512, 256, 0, stream>>>(yb, wob, bo, (float*)d_out);
}

// Round 9
// 160.459 us; speedup vs baseline: 1.0302x; 1.0302x over previous
//
#include <hip/hip_runtime.h>
#include <hip/hip_bf16.h>
#include <cstdint>

typedef __attribute__((ext_vector_type(8))) short short8;
typedef __attribute__((ext_vector_type(4))) short short4v;
typedef __attribute__((ext_vector_type(4))) float f32x4;
typedef __attribute__((ext_vector_type(16))) float f32x16;
typedef __attribute__((ext_vector_type(4))) unsigned int u32x4;
typedef unsigned short ushort_t;
typedef unsigned int uint32;

#define DEVI static __device__ __forceinline__

DEVI ushort_t f2bf(float f){
  uint32 u = __builtin_bit_cast(uint32, f);
  u += 0x7FFFu + ((u >> 16) & 1u);
  return (ushort_t)(u >> 16);
}
DEVI float bf2f(ushort_t s){
  uint32 u = ((uint32)s) << 16;
  return __builtin_bit_cast(float, u);
}
DEVI uint32 cvtpk_bf16(float lo, float hi){
  uint32 r;
  asm("v_cvt_pk_bf16_f32 %0, %1, %2" : "=v"(r) : "v"(lo), "v"(hi));
  return r;
}
DEVI void plswap(uint32& a, uint32& b){
  asm("v_permlane32_swap_b32 %0, %1" : "+v"(a), "+v"(b));
}

typedef __attribute__((address_space(1))) const uint32 g_u32;
typedef __attribute__((address_space(3))) uint32 l_u32;
#define GL_LDS16(gp, lp) __builtin_amdgcn_global_load_lds((g_u32*)(gp), (l_u32*)(lp), 16, 0, 0)

#define MFMA16(a, b, c) __builtin_amdgcn_mfma_f32_16x16x32_bf16(a, b, c, 0, 0, 0)

// ---------------- fp32 -> bf16 conversion + rope table ----------------
__global__ __launch_bounds__(256) void convert_all(
    const float* __restrict__ x, const float* __restrict__ wq, const float* __restrict__ wk,
    const float* __restrict__ wv, const float* __restrict__ wo,
    ushort_t* __restrict__ xb, ushort_t* __restrict__ wqkv, ushort_t* __restrict__ wob,
    float2* __restrict__ tab){
  int bid = blockIdx.x;
  if (bid >= 6144){
    // rope table: [2048 tok][32 j] float2
    const int idx = (bid - 6144) * 256 + threadIdx.x;    // 65536
    const int tok = idx >> 5, j = idx & 31;
    const float theta = exp2f(-(float)j * 0.4152410118609203f);   // log2(10000)/32
    const float ang = (float)(tok + 1) * theta;
    float s, c;
    sincosf(ang, &s, &c);
    tab[idx] = make_float2(c, s);
    return;
  }
  const float* src; ushort_t* dst; long base;
  if (bid < 4096){ src = x; dst = xb; base = (long)bid * 2048; }
  else {
    int r = bid - 4096; int sel = r >> 9; int o = r & 511;
    src = sel==0?wq: sel==1?wk: sel==2?wv: wo;
    dst = (sel<3) ? (wqkv + (long)sel * 1048576) : wob;
    base = (long)o * 2048;
  }
  long i = base + (long)threadIdx.x * 8;
  const float* p = src + i;
  float4 a = *(const float4*)p;
  float4 b = *(const float4*)(p + 4);
  short8 v;
  v[0]=(short)f2bf(a.x); v[1]=(short)f2bf(a.y); v[2]=(short)f2bf(a.z); v[3]=(short)f2bf(a.w);
  v[4]=(short)f2bf(b.x); v[5]=(short)f2bf(b.y); v[6]=(short)f2bf(b.z); v[7]=(short)f2bf(b.w);
  *(short8*)(dst + i) = v;
}

// ---------------- QKV GEMM, 256x128 tile, BK=64, tri-buffered 2-phase ----------------
// XCD-resident mapping: each XCD owns an (8 bm x 12 bn) region, dispatched in
// rounds of 8 bm x 4 bn -> concurrent L2 working set ~= 4MB A + 1MB B.
__global__ __launch_bounds__(512, 2) void gemm_qkv(
    const ushort_t* __restrict__ A, const ushort_t* __restrict__ Bw,
    const float* __restrict__ bq, const float* __restrict__ bk, const float* __restrict__ bv,
    const float2* __restrict__ tab,
    ushort_t* __restrict__ Qb, ushort_t* __restrict__ Kb, ushort_t* __restrict__ Vt){
  __shared__ __align__(16) ushort_t S[73728];   // 144 KB
  const int tid = threadIdx.x;
  const int w = tid >> 6, l = tid & 63, lr = l & 15, lg = l >> 4;
  const int wm = w >> 1, wn = w & 1;            // 4M x 2N
  // mapping: xcd region (8bm x 12bn), rounds of 8bm x 4bn
  const int xcd = blockIdx.x & 7;
  const int l9  = blockIdx.x >> 3;              // 0..95
  const int bg  = l9 >> 5;                      // 0..2 (bn group of 4)
  const int rem = l9 & 31;
  const int bm  = ((xcd & 3) << 3) + (rem >> 2);
  const int bn  = ((xcd >> 2) * 12) + (bg << 2) + (rem & 3);
  const int m0 = bm << 8, n0 = bn << 7;
  // staging: thread covers row tid>>2 (+128 for A's 2nd load), 16B chunk tid&3
  const int rbase = tid >> 2;
  const int swzk = (tid & 3) ^ ((tid >> 3) & 3);
  const ushort_t* aS = A  + (long)(m0 + rbase) * 1024 + swzk * 8;
  const ushort_t* bS = Bw + (long)(n0 + rbase) * 1024 + swzk * 8;
  // ds_read swizzled slot
  const int slot = (lg ^ ((lr >> 1) & 3)) << 3;
  const int arow = wm * 64 + lr;          // + mi*16
  const int brow = wn * 64 + lr;          // + nc*16
  f32x4 acc[4][4] = {};

#define STGA(kk, t, bf_) do{ \
    const ushort_t* _s = aS + (long)(t)*64 + (kk)*32; \
    ushort_t* _d = &S[(bf_)*24576 + (kk)*8192 + tid*8]; \
    GL_LDS16(_s,          _d); \
    GL_LDS16(_s + 131072, _d + 4096); }while(0)
#define STGB(kk, t, bf_) do{ \
    GL_LDS16(bS + (long)(t)*64 + (kk)*32, \
             &S[(bf_)*24576 + 16384 + (kk)*4096 + tid*8]); }while(0)

  // prologue: tiles 0 and 1 fully issued (12 loads); tile 0 resident
  STGA(0,0,0); STGB(0,0,0); STGA(1,0,0); STGB(1,0,0);
  STGA(0,1,1); STGB(0,1,1); STGA(1,1,1); STGB(1,1,1);
  asm volatile("s_waitcnt vmcnt(6)" ::: "memory");
  __builtin_amdgcn_s_barrier();

  int buf = 0;
  for (int t = 0; t < 16; ++t){
    const int nstg = (buf >= 1) ? buf - 1 : 2;     // (t+2)%3
    const ushort_t* SA = &S[buf * 24576];
    const ushort_t* SB = &S[buf * 24576 + 16384];
    short8 af[4], bfv[4];
    // ---- phase 0 (kk0)
#pragma unroll
    for (int mi = 0; mi < 4; ++mi) af[mi]  = *(const short8*)&SA[(arow + mi*16)*32 + slot];
#pragma unroll
    for (int nc = 0; nc < 4; ++nc) bfv[nc] = *(const short8*)&SB[(brow + nc*16)*32 + slot];
    if (t < 14){ STGA(0, t+2, nstg); STGB(0, t+2, nstg); }
    __builtin_amdgcn_s_barrier();
    __builtin_amdgcn_s_setprio(1);
#pragma unroll
    for (int mi = 0; mi < 4; ++mi)
#pragma unroll
      for (int nc = 0; nc < 4; ++nc)
        acc[mi][nc] = MFMA16(af[mi], bfv[nc], acc[mi][nc]);
    __builtin_amdgcn_s_setprio(0);
    __builtin_amdgcn_s_barrier();
    // ---- phase 1 (kk1)
#pragma unroll
    for (int mi = 0; mi < 4; ++mi) af[mi]  = *(const short8*)&SA[8192 + (arow + mi*16)*32 + slot];
#pragma unroll
    for (int nc = 0; nc < 4; ++nc) bfv[nc] = *(const short8*)&SB[4096 + (brow + nc*16)*32 + slot];
    if (t < 14){ STGA(1, t+2, nstg); STGB(1, t+2, nstg); }
    __builtin_amdgcn_s_barrier();
    __builtin_amdgcn_s_setprio(1);
#pragma unroll
    for (int mi = 0; mi < 4; ++mi)
#pragma unroll
      for (int nc = 0; nc < 4; ++nc)
        acc[mi][nc] = MFMA16(af[mi], bfv[nc], acc[mi][nc]);
    __builtin_amdgcn_s_setprio(0);
    if (t < 14)       asm volatile("s_waitcnt vmcnt(6)" ::: "memory");  // tile t+1 resident
    else if (t == 14) asm volatile("s_waitcnt vmcnt(0)" ::: "memory");  // tile 15 resident
    __builtin_amdgcn_s_barrier();
    buf = (buf >= 2) ? 0 : buf + 1;
  }
#undef STGA
#undef STGB

  // epilogue: bias + rope + scatter (wave spans exactly one head's 64 dims)
  const int colX = n0 + (wn << 6);
  const int sel = colX >> 10;                // 0=Q 1=K 2=V
  const int h = (colX >> 6) & 15;
  const int cB = (colX & 1023) + lr;
  if (sel < 2){
    ushort_t* dst = sel ? Kb : Qb;
    const float* bp = sel ? bk : bq;
    const float bvs[4] = {bp[cB], bp[cB+16], bp[cB+32], bp[cB+48]};
#pragma unroll
    for (int mi = 0; mi < 4; ++mi){
      const int row0 = m0 + (wm << 6) + mi*16 + lg*4;
#pragma unroll
      for (int i = 0; i < 4; ++i){
        const int r = row0 + i;
        const int b = r >> 11, tok = r & 2047;
#pragma unroll
        for (int nc = 0; nc < 2; ++nc){
          const int j = nc*16 + lr;
          const float2 cs = tab[tok*32 + j];
          const float v0 = acc[mi][nc][i]   + bvs[nc];
          const float v1 = acc[mi][nc+2][i] + bvs[nc+2];
          const long base = (((long)((b<<4) + h) * 2048 + tok) << 6) + j;
          dst[base]      = f2bf(v0 * cs.x - v1 * cs.y);
          dst[base + 32] = f2bf(v1 * cs.x + v0 * cs.y);
        }
      }
    }
  } else {
    const float bvs[4] = {bv[cB], bv[cB+16], bv[cB+32], bv[cB+48]};
#pragma unroll
    for (int mi = 0; mi < 4; ++mi){
      const int row0 = m0 + (wm << 6) + mi*16 + lg*4;
#pragma unroll
      for (int nc = 0; nc < 4; ++nc){
        const int d = nc*16 + lr;
#pragma unroll
        for (int i = 0; i < 4; ++i){
          const int r = row0 + i;
          const int b = r >> 11, tok = r & 2047;
          Vt[((long)((b<<4) + h) * 64 + d) * 2048 + tok] = f2bf(acc[mi][nc][i] + bvs[nc]);
        }
      }
    }
  }
}

// ---------------- output GEMM, 256x128, BK=64, tri-buffered (fp32 out) ----------------
// grid 256 = 1 block/CU; per-XCD region 4bm x 8bn -> L2 working set 2MB A + 2MB B.
__global__ __launch_bounds__(512, 2) void gemm_out(
    const ushort_t* __restrict__ A, const ushort_t* __restrict__ Bw,
    const float* __restrict__ bias, float* __restrict__ Cout){
  __shared__ __align__(16) ushort_t S[73728];   // 144 KB
  const int tid = threadIdx.x;
  const int w = tid >> 6, l = tid & 63, lr = l & 15, lg = l >> 4;
  const int wm = w >> 1, wn = w & 1;
  const int xcd = blockIdx.x & 7;
  const int l9  = blockIdx.x >> 3;              // 0..31
  const int bm  = (xcd << 2) + (l9 >> 3);
  const int bn  = l9 & 7;
  const int m0 = bm << 8, n0 = bn << 7;
  const int rbase = tid >> 2;
  const int swzk = (tid & 3) ^ ((tid >> 3) & 3);
  const ushort_t* aS = A  + (long)(m0 + rbase) * 1024 + swzk * 8;
  const ushort_t* bS = Bw + (long)(n0 + rbase) * 1024 + swzk * 8;
  const int slot = (lg ^ ((lr >> 1) & 3)) << 3;
  const int arow = wm * 64 + lr;
  const int brow = wn * 64 + lr;
  f32x4 acc[4][4] = {};

#define STGA(kk, t, bf_) do{ \
    const ushort_t* _s = aS + (long)(t)*64 + (kk)*32; \
    ushort_t* _d = &S[(bf_)*24576 + (kk)*8192 + tid*8]; \
    GL_LDS16(_s,          _d); \
    GL_LDS16(_s + 131072, _d + 4096); }while(0)
#define STGB(kk, t, bf_) do{ \
    GL_LDS16(bS + (long)(t)*64 + (kk)*32, \
             &S[(bf_)*24576 + 16384 + (kk)*4096 + tid*8]); }while(0)

  STGA(0,0,0); STGB(0,0,0); STGA(1,0,0); STGB(1,0,0);
  STGA(0,1,1); STGB(0,1,1); STGA(1,1,1); STGB(1,1,1);
  asm volatile("s_waitcnt vmcnt(6)" ::: "memory");
  __builtin_amdgcn_s_barrier();

  int buf = 0;
  for (int t = 0; t < 16; ++t){
    const int nstg = (buf >= 1) ? buf - 1 : 2;
    const ushort_t* SA = &S[buf * 24576];
    const ushort_t* SB = &S[buf * 24576 + 16384];
    short8 af[4], bfv[4];
#pragma unroll
    for (int mi = 0; mi < 4; ++mi) af[mi]  = *(const short8*)&SA[(arow + mi*16)*32 + slot];
#pragma unroll
    for (int nc = 0; nc < 4; ++nc) bfv[nc] = *(const short8*)&SB[(brow + nc*16)*32 + slot];
    if (t < 14){ STGA(0, t+2, nstg); STGB(0, t+2, nstg); }
    __builtin_amdgcn_s_barrier();
    __builtin_amdgcn_s_setprio(1);
#pragma unroll
    for (int mi = 0; mi < 4; ++mi)
#pragma unroll
      for (int nc = 0; nc < 4; ++nc)
        acc[mi][nc] = MFMA16(af[mi], bfv[nc], acc[mi][nc]);
    __builtin_amdgcn_s_setprio(0);
    __builtin_amdgcn_s_barrier();
#pragma unroll
    for (int mi = 0; mi < 4; ++mi) af[mi]  = *(const short8*)&SA[8192 + (arow + mi*16)*32 + slot];
#pragma unroll
    for (int nc = 0; nc < 4; ++nc) bfv[nc] = *(const short8*)&SB[4096 + (brow + nc*16)*32 + slot];
    if (t < 14){ STGA(1, t+2, nstg); STGB(1, t+2, nstg); }
    __builtin_amdgcn_s_barrier();
    __builtin_amdgcn_s_setprio(1);
#pragma unroll
    for (int mi = 0; mi < 4; ++mi)
#pragma unroll
      for (int nc = 0; nc < 4; ++nc)
        acc[mi][nc] = MFMA16(af[mi], bfv[nc], acc[mi][nc]);
    __builtin_amdgcn_s_setprio(0);
    if (t < 14)       asm volatile("s_waitcnt vmcnt(6)" ::: "memory");
    else if (t == 14) asm volatile("s_waitcnt vmcnt(0)" ::: "memory");
    __builtin_amdgcn_s_barrier();
    buf = (buf >= 2) ? 0 : buf + 1;
  }
#undef STGA
#undef STGB

  const int colBase = n0 + (wn << 6) + lr;
#pragma unroll
  for (int mi = 0; mi < 4; ++mi){
    const int row0 = m0 + (wm << 6) + mi*16 + lg*4;
#pragma unroll
    for (int nc = 0; nc < 4; ++nc){
      const int col = colBase + nc*16;
      const float bvv = bias[col];
#pragma unroll
      for (int i = 0; i < 4; ++i)
        Cout[(long)(row0 + i) * 1024 + col] = acc[mi][nc][i] + bvv;
    }
  }
}

// ---------------- flash attention (causal), 8-wave block, LDS-staged K/V ----------------
// Counted-vmcnt pipeline: stage(kt+1) issued at top; vmcnt(1) ensures stage(kt)
// done (one iteration of slack); two raw s_barriers, never a vmcnt(0) drain.
__global__ __launch_bounds__(512, 4) void attn(
    const ushort_t* __restrict__ Qb, const ushort_t* __restrict__ Kb,
    const ushort_t* __restrict__ Vt, ushort_t* __restrict__ yb){
  __shared__ __align__(16) ushort_t Ks[2][2048];
  __shared__ __align__(16) ushort_t Vs[2][2048];
  const int tid = threadIdx.x;
  const int w = tid >> 6, l = tid & 63;
  const int lq = l & 31;
  const int hi = l >> 5;
  const int xcd = blockIdx.x & 7;
  const int idx = blockIdx.x >> 3;          // 0..63
  const int hi5 = idx >> 5;                 // 0/1
  const int bh  = (xcd << 3) + ((idx >> 3) & 3) + hi5 * 4;
  const int qj  = hi5 ? (idx & 7) : 7 - (idx & 7);
  const int qc = (qj << 3) + w;
  const int q0 = qc << 5;
  const int ktmax = (qj << 3) + 7;
  const ushort_t* Qh = Qb + (long)bh * 2048 * 64;
  const ushort_t* Kh = Kb + (long)bh * 2048 * 64;
  const ushort_t* Vth = Vt + (long)bh * 64 * 2048;
  const int h8 = hi * 8;

  const ushort_t* qp = &Qh[(long)(q0 + lq) * 64 + h8];
  short8 qf0 = *(const short8*)(qp);
  short8 qf1 = *(const short8*)(qp + 16);
  short8 qf2 = *(const short8*)(qp + 32);
  short8 qf3 = *(const short8*)(qp + 48);

  const int stg_is_v = (w >= 4);
  long stg_src_off; int stg_dst_off;
  if (!stg_is_v){
    const int row = (w << 3) + (l >> 3);               // 0..31
    const int cl  = (l & 7) ^ (row & 7);
    stg_src_off = ((long)row << 6) + (cl << 3);
    stg_dst_off = (w << 9) + (l << 3);
  } else {
    const int row = ((w - 4) << 3) + (l >> 3);         // 0..31
    const int cl  = (l & 7) ^ (row & 7);
    const int dd  = row + ((cl & 4) << 3);
    stg_src_off = ((long)dd << 11) + ((cl & 3) << 3);
    stg_dst_off = ((w - 4) << 9) + (l << 3);
  }

  f32x16 o0 = {}, o1 = {};
  float lsum = 0.f;
  const float cl2 = 0.1803368801111204f;

  if (!stg_is_v) GL_LDS16(Kh + stg_src_off,  &Ks[0][stg_dst_off]);
  else           GL_LDS16(Vth + stg_src_off, &Vs[0][stg_dst_off]);
  asm volatile("s_waitcnt vmcnt(0)" ::: "memory");
  __builtin_amdgcn_s_barrier();

  int cur = 0;
  for (int kt = 0; kt <= ktmax; ++kt){
    if (kt < ktmax){
      const int k0n = (kt + 1) << 5;
      if (!stg_is_v) GL_LDS16(Kh + ((long)k0n << 6) + stg_src_off, &Ks[cur ^ 1][stg_dst_off]);
      else           GL_LDS16(Vth + k0n + stg_src_off,             &Vs[cur ^ 1][stg_dst_off]);
      asm volatile("s_waitcnt vmcnt(1)" ::: "memory");   // own stage(kt) done
    } else {
      asm volatile("s_waitcnt vmcnt(0)" ::: "memory");
    }
    __builtin_amdgcn_s_barrier();      // all waves' stage(kt) visible
    if (kt <= qc){
      const int swk = lq & 7;
      const ushort_t* kr = &Ks[cur][lq << 6];
      short8 kf0 = *(const short8*)&kr[((hi    ) ^ swk) << 3];
      short8 kf1 = *(const short8*)&kr[((2 + hi) ^ swk) << 3];
      short8 kf2 = *(const short8*)&kr[((4 + hi) ^ swk) << 3];
      short8 kf3 = *(const short8*)&kr[((6 + hi) ^ swk) << 3];
      const ushort_t* vr = &Vs[cur][lq << 6];
      short8 vf00 = *(const short8*)&vr[((hi    ) ^ swk) << 3];
      short8 vf01 = *(const short8*)&vr[((2 + hi) ^ swk) << 3];
      short8 vf10 = *(const short8*)&vr[((4 + hi) ^ swk) << 3];
      short8 vf11 = *(const short8*)&vr[((6 + hi) ^ swk) << 3];
      f32x16 s = {};
      s = __builtin_amdgcn_mfma_f32_32x32x16_bf16(kf0, qf0, s, 0, 0, 0);
      s = __builtin_amdgcn_mfma_f32_32x32x16_bf16(kf1, qf1, s, 0, 0, 0);
      s = __builtin_amdgcn_mfma_f32_32x32x16_bf16(kf2, qf2, s, 0, 0, 0);
      s = __builtin_amdgcn_mfma_f32_32x32x16_bf16(kf3, qf3, s, 0, 0, 0);
      if (kt == qc){
#pragma unroll
        for (int r = 0; r < 16; ++r){
          const int rk = (r & 3) + 8 * (r >> 2) + 4 * hi;
          if (rk > lq) s[r] = -1e30f;
        }
      }
#pragma unroll
      for (int r = 0; r < 16; ++r) s[r] = __builtin_amdgcn_exp2f(__builtin_fmaf(s[r], cl2, -2.0f));
      {
        float t0 = (s[0] + s[1]) + (s[2] + s[3]);
        float t1 = (s[4] + s[5]) + (s[6] + s[7]);
        float t2 = (s[8] + s[9]) + (s[10] + s[11]);
        float t3 = (s[12] + s[13]) + (s[14] + s[15]);
        lsum += (t0 + t1) + (t2 + t3);
      }
      uint32 a0 = cvtpk_bf16(s[0], s[1]),  b0 = cvtpk_bf16(s[4], s[5]);
      uint32 a1 = cvtpk_bf16(s[2], s[3]),  b1 = cvtpk_bf16(s[6], s[7]);
      uint32 a2 = cvtpk_bf16(s[8], s[9]),  b2 = cvtpk_bf16(s[12], s[13]);
      uint32 a3 = cvtpk_bf16(s[10], s[11]),b3 = cvtpk_bf16(s[14], s[15]);
      plswap(a0, b0);
      plswap(a1, b1);
      plswap(a2, b2);
      plswap(a3, b3);
      u32x4 pc0 = {a0, a1, b0, b1};
      u32x4 pc1 = {a2, a3, b2, b3};
      short8 pb0 = __builtin_bit_cast(short8, pc0);
      short8 pb1 = __builtin_bit_cast(short8, pc1);
      o0 = __builtin_amdgcn_mfma_f32_32x32x16_bf16(vf00, pb0, o0, 0, 0, 0);
      o0 = __builtin_amdgcn_mfma_f32_32x32x16_bf16(vf01, pb1, o0, 0, 0, 0);
      o1 = __builtin_amdgcn_mfma_f32_32x32x16_bf16(vf10, pb0, o1, 0, 0, 0);
      o1 = __builtin_amdgcn_mfma_f32_32x32x16_bf16(vf11, pb1, o1, 0, 0, 0);
    }
    __builtin_amdgcn_s_barrier();      // all waves done reading buf cur
    cur ^= 1;
  }
  lsum += __shfl_xor(lsum, 32);
  const float inv = 1.0f / lsum;
  const int b = bh >> 4, h = bh & 15;
  const int tok = q0 + lq;
  ushort_t* yrow = yb + (long)(b * 2048 + tok) * 1024 + h * 64;
#pragma unroll
  for (int g = 0; g < 4; ++g){
    short4v p0, p1;
#pragma unroll
    for (int j = 0; j < 4; ++j){
      p0[j] = (short)f2bf(o0[4*g + j] * inv);
      p1[j] = (short)f2bf(o1[4*g + j] * inv);
    }
    *(short4v*)&yrow[8*g + 4*hi]      = p0;
    *(short4v*)&yrow[32 + 8*g + 4*hi] = p1;
  }
}

// ---------------- launch ----------------
extern "C" void kernel_launch(void* const* d_in, const int* in_sizes, int n_in,
                              void* d_out, int out_size, void* d_ws, size_t ws_size,
                              hipStream_t stream){
  const float* x  = (const float*)d_in[0];
  const float* Wq = (const float*)d_in[1];
  const float* bq = (const float*)d_in[2];
  const float* Wk = (const float*)d_in[3];
  const float* bk = (const float*)d_in[4];
  const float* Wv = (const float*)d_in[5];
  const float* bv = (const float*)d_in[6];
  const float* Wo = (const float*)d_in[7];
  const float* bo = (const float*)d_in[8];
  char* ws = (char*)d_ws;
  ushort_t* xb   = (ushort_t*)(ws);                      // 16 MB; reused as yb after attn
  ushort_t* wqkv = (ushort_t*)(ws + 16777216);           // 6 MB (Q,K,V packed)
  ushort_t* wob  = (ushort_t*)(ws + 23068672);           // 2 MB
  float2*   tab  = (float2*)  (ws + 25165824);           // 512 KB
  ushort_t* Qb   = (ushort_t*)(ws + 25690112);           // 16 MB
  ushort_t* Kb   = (ushort_t*)(ws + 42467328);           // 16 MB
  ushort_t* Vt   = (ushort_t*)(ws + 59244544);           // 16 MB
  ushort_t* yb   = xb;

  convert_all<<<6400, 256, 0, stream>>>(x, Wq, Wk, Wv, Wo, xb, wqkv, wob, tab);
  gemm_qkv<<<768, 512, 0, stream>>>(xb, wqkv, bq, bk, bv, tab, Qb, Kb, Vt);
  attn<<<512, 512, 0, stream>>>(Qb, Kb, Vt, yb);
  gemm_out<<<256, 512, 0, stream>>>(yb, wob, bo, (float*)d_out);
}